// Round 2
// baseline (9873.040 us; speedup 1.0000x reference)
//
#include <hip/hip_runtime.h>
#include <cmath>

#define LOG2E 1.44269504088896340736f
#define TMAX 2048

#if __has_builtin(__builtin_amdgcn_exp2f)
#define EXP2F(x) __builtin_amdgcn_exp2f(x)
#else
#define EXP2F(x) exp2f(x)
#endif
#if __has_builtin(__builtin_amdgcn_rcpf)
#define RCPF(x) __builtin_amdgcn_rcpf(x)
#else
#define RCPF(x) (1.0f / (x))
#endif

__device__ __forceinline__ float fexp(float x)  { return EXP2F(x * LOG2E); }
// tanh(x) = 1 - 2/(1 + e^{2x})
__device__ __forceinline__ float ftanh(float x) { return 1.0f - 2.0f * RCPF(1.0f + EXP2F(x * (2.0f * LOG2E))); }
// _step(x) = (tanh(5x)+1)/2 = sigmoid(10x)
__device__ __forceinline__ float fstep(float x) { return RCPF(1.0f + EXP2F(x * (-10.0f * LOG2E))); }
__device__ __forceinline__ float fsinh(float x) { float e = fexp(x); return 0.5f * (e - RCPF(e)); }

// broadcast lane `l`'s value of x to all lanes (result is wave-uniform, lands in SGPR)
__device__ __forceinline__ float rl(float x, int l) {
    return __builtin_bit_cast(float, __builtin_amdgcn_readlane(__builtin_bit_cast(int, x), l));
}

__device__ __forceinline__ int fadd_i(int a, int b) {
    return __builtin_bit_cast(int, __builtin_bit_cast(float, a) + __builtin_bit_cast(float, b));
}

// full-wave (64 lane) sum via DPP tree; returns the total as a wave-uniform value.
// Pure VALU: row_shr 1/2/4/8 then row_bcast15 (rows 1,3), row_bcast31 (rows 2,3);
// lane 63 holds the total, readlane broadcasts it.
__device__ __forceinline__ float wave_allsum(float x) {
    int v = __builtin_bit_cast(int, x);
    v = fadd_i(v, __builtin_amdgcn_update_dpp(0, v, 0x111, 0xF, 0xF, true)); // row_shr:1
    v = fadd_i(v, __builtin_amdgcn_update_dpp(0, v, 0x112, 0xF, 0xF, true)); // row_shr:2
    v = fadd_i(v, __builtin_amdgcn_update_dpp(0, v, 0x114, 0xF, 0xF, true)); // row_shr:4
    v = fadd_i(v, __builtin_amdgcn_update_dpp(0, v, 0x118, 0xF, 0xF, true)); // row_shr:8
    v = fadd_i(v, __builtin_amdgcn_update_dpp(0, v, 0x142, 0xA, 0xF, true)); // row_bcast:15 -> rows 1,3
    v = fadd_i(v, __builtin_amdgcn_update_dpp(0, v, 0x143, 0xC, 0xF, true)); // row_bcast:31 -> rows 2,3
    return __builtin_bit_cast(float, __builtin_amdgcn_readlane(v, 63));
}

// 64x64 matvec: lane i holds column i of W in w[0..63]; xlane is x[lane].
// Broadcast each x[j] via readlane (SGPR operand of the FMA) -- no LDS on the
// critical path. 4 independent accumulator chains.
__device__ __forceinline__ float matvec64(const float (&w)[64], float xlane, float bias) {
    float a0 = bias, a1 = 0.0f, a2 = 0.0f, a3 = 0.0f;
#pragma unroll
    for (int j = 0; j < 64; j += 4) {
        a0 = fmaf(w[j + 0], rl(xlane, j + 0), a0);
        a1 = fmaf(w[j + 1], rl(xlane, j + 1), a1);
        a2 = fmaf(w[j + 2], rl(xlane, j + 2), a2);
        a3 = fmaf(w[j + 3], rl(xlane, j + 3), a3);
    }
    return (a0 + a1) + (a2 + a3);
}

__global__ __launch_bounds__(64, 1)
void exphydro_kernel(const float* __restrict__ g_snow, const float* __restrict__ g_water,
                     const float* __restrict__ g_pr, const float* __restrict__ g_tm,
                     const float* __restrict__ g_ld, const float* __restrict__ g_t,
                     const float* __restrict__ W1, const float* __restrict__ b1,
                     const float* __restrict__ W2, const float* __restrict__ b2,
                     const float* __restrict__ W3, const float* __restrict__ b3,
                     const float* __restrict__ W4, const float* __restrict__ b4,
                     float* __restrict__ out, int T)
{
    const int lane = threadIdx.x;
    const int b = blockIdx.x;

    __shared__ __align__(16) float s_pr[TMAX];
    __shared__ __align__(16) float s_tm[TMAX];
    __shared__ __align__(16) float s_ld[TMAX];
    __shared__ __align__(16) float s_t[TMAX];

    // stage forcing series (this sample's rows) + time into LDS, coalesced
    for (int i = lane; i < T; i += 64) {
        s_pr[i] = g_pr[b * T + i];
        s_tm[i] = g_tm[b * T + i];
        s_ld[i] = g_ld[b * T + i];
        s_t[i]  = g_t[i];
    }

    // weights: lane i holds column i of W1/W2/W3 and row i of W4
    float w1r[4], w2r[64], w3r[64], w4r[5], b4r[5];
#pragma unroll
    for (int j = 0; j < 4; ++j) w1r[j] = W1[j * 64 + lane];
    float b1v = b1[lane];
#pragma unroll
    for (int j = 0; j < 64; ++j) w2r[j] = W2[j * 64 + lane];
    float b2v = b2[lane];
#pragma unroll
    for (int j = 0; j < 64; ++j) w3r[j] = W3[j * 64 + lane];
    float b3v = b3[lane];
#pragma unroll
    for (int k = 0; k < 5; ++k) { w4r[k] = W4[lane * 5 + k]; b4r[k] = b4[k]; }

    __syncthreads();

    // MLP: x (wave-uniform) -> o[5] (wave-uniform). No LDS anywhere.
    auto mlp5 = [&](float x0, float x1, float x2, float x3, float* o) {
        // layer 1: 4 -> 64 (lane = hidden unit; inputs are uniform)
        float h1 = ftanh(fmaf(w1r[3], x3, fmaf(w1r[2], x2, fmaf(w1r[1], x1, fmaf(w1r[0], x0, b1v)))));
        // layer 2: 64 -> 64 via readlane broadcast
        float h2 = ftanh(matvec64(w2r, h1, b2v));
        // layer 3: 64 -> 64
        float h3 = ftanh(matvec64(w3r, h2, b3v));
        // layer 4: 64 -> 5 via DPP tree reductions (5 independent chains)
        float p0 = w4r[0] * h3, p1 = w4r[1] * h3, p2 = w4r[2] * h3,
              p3 = w4r[3] * h3, p4 = w4r[4] * h3;
        o[0] = wave_allsum(p0) + b4r[0];
        o[1] = wave_allsum(p1) + b4r[1];
        o[2] = wave_allsum(p2) + b4r[2];
        o[3] = wave_allsum(p3) + b4r[3];
        o[4] = wave_allsum(p4) + b4r[4];
    };

    auto interp_at = [&](float tv, float& pr, float& tm, float& ld) {
        int i0 = (int)floorf(tv);
        if (i0 < 0) i0 = 0;
        if (i0 > T - 2) i0 = T - 2;
        float fr = tv - (float)i0;
        float w0 = 1.0f - fr;
        pr = s_pr[i0] * w0 + s_pr[i0 + 1] * fr;
        tm = s_tm[i0] * w0 + s_tm[i0 + 1] * fr;
        ld = s_ld[i0] * w0 + s_ld[i0 + 1] * fr;
    };

    auto rhs = [&](float y0v, float y1v, float pr, float tm, float ld,
                   float& d0, float& d1, float& o4) {
        float o[5];
        mlp5(y0v, y1v, pr, tm, o);
        float psnow = fmaxf(0.0f, fsinh(o[0]) * fstep(-tm));
        float prain = fmaxf(0.0f, fsinh(o[1]));
        float melt  = fmaxf(0.0f, fstep(y0v) * fsinh(o[2]));
        float st1   = fstep(y1v);
        float et    = st1 * fexp(o[3]) * ld;
        float qq    = st1 * fexp(o[4]);
        d0 = psnow - melt;
        d1 = prain + melt - et - qq;
        o4 = o[4];
    };

    float y0v = g_snow[b * T];
    float y1v = g_water[b * T];

    for (int st = 0; st < T - 1; ++st) {
        float t0 = s_t[st], t1 = s_t[st + 1];
        float dt = t1 - t0, half = 0.5f * dt;

        // fetch all three interp points up-front (k2..k4 forcing values hidden under k1)
        float prA, tmA, ldA, prH, tmH, ldH, prC, tmC, ldC;
        interp_at(t0, prA, tmA, ldA);
        interp_at(t0 + half, prH, tmH, ldH);
        interp_at(t0 + dt, prC, tmC, ldC);

        float k1a, k1b, k2a, k2b, k3a, k3b, k4a, k4b, o4, o4x;
        rhs(y0v, y1v, prA, tmA, ldA, k1a, k1b, o4);
        // q_out[:, st] == o[4] of the k1 MLP evaluation (integer-time interp == raw series)
        if (lane == 0) out[b * T + st] = o4;
        rhs(y0v + half * k1a, y1v + half * k1b, prH, tmH, ldH, k2a, k2b, o4x);
        rhs(y0v + half * k2a, y1v + half * k2b, prH, tmH, ldH, k3a, k3b, o4x);
        rhs(y0v + dt * k3a,   y1v + dt * k3b,  prC, tmC, ldC, k4a, k4b, o4x);

        float c = dt * (1.0f / 6.0f);
        y0v = fmaf(c, k1a + 2.0f * k2a + 2.0f * k3a + k4a, y0v);
        y1v = fmaf(c, k1b + 2.0f * k2b + 2.0f * k3b + k4b, y1v);
    }

    // last readout at t = T-1 with raw series values and final state
    {
        float o[5];
        mlp5(y0v, y1v, s_pr[T - 1], s_tm[T - 1], o);
        if (lane == 0) out[b * T + (T - 1)] = o[4];
    }
}

extern "C" void kernel_launch(void* const* d_in, const int* in_sizes, int n_in,
                              void* d_out, int out_size, void* d_ws, size_t ws_size,
                              hipStream_t stream) {
    const float* g_snow  = (const float*)d_in[0];
    const float* g_water = (const float*)d_in[1];
    const float* g_pr    = (const float*)d_in[2];
    const float* g_tm    = (const float*)d_in[3];
    const float* g_ld    = (const float*)d_in[4];
    const float* g_t     = (const float*)d_in[5];
    const float* W1 = (const float*)d_in[6];
    const float* b1 = (const float*)d_in[7];
    const float* W2 = (const float*)d_in[8];
    const float* b2 = (const float*)d_in[9];
    const float* W3 = (const float*)d_in[10];
    const float* b3 = (const float*)d_in[11];
    const float* W4 = (const float*)d_in[12];
    const float* b4 = (const float*)d_in[13];

    const int T = in_sizes[5];
    const int B = in_sizes[0] / T;

    exphydro_kernel<<<dim3(B), dim3(64), 0, stream>>>(
        g_snow, g_water, g_pr, g_tm, g_ld, g_t,
        W1, b1, W2, b2, W3, b3, W4, b4,
        (float*)d_out, T);
}

// Round 3
// 6576.028 us; speedup vs baseline: 1.5014x; 1.5014x over previous
//
#include <hip/hip_runtime.h>
#include <cmath>

#define LOG2E 1.44269504088896340736f
#define TMAX 2048

#if __has_builtin(__builtin_amdgcn_exp2f)
#define EXP2F(x) __builtin_amdgcn_exp2f(x)
#else
#define EXP2F(x) exp2f(x)
#endif
#if __has_builtin(__builtin_amdgcn_rcpf)
#define RCPF(x) __builtin_amdgcn_rcpf(x)
#else
#define RCPF(x) (1.0f / (x))
#endif

typedef float float2v __attribute__((ext_vector_type(2)));
typedef float float4v __attribute__((ext_vector_type(4)));

__device__ __forceinline__ float fexp(float x)  { return EXP2F(x * LOG2E); }
// tanh(x) = 1 - 2/(1 + e^{2x})
__device__ __forceinline__ float ftanh(float x) { return 1.0f - 2.0f * RCPF(1.0f + EXP2F(x * (2.0f * LOG2E))); }
// _step(x) = (tanh(5x)+1)/2 = sigmoid(10x)
__device__ __forceinline__ float fstep(float x) { return RCPF(1.0f + EXP2F(x * (-10.0f * LOG2E))); }
__device__ __forceinline__ float fsinh(float x) { float e = fexp(x); return 0.5f * (e - RCPF(e)); }

__device__ __forceinline__ int fadd_i(int a, int b) {
    return __builtin_bit_cast(int, __builtin_bit_cast(float, a) + __builtin_bit_cast(float, b));
}

// full-wave (64 lane) sum via DPP tree; wave-uniform result.
// row_shr 1/2/4/8, row_bcast:15 (rows 1,3), row_bcast:31 (rows 2,3); lane 63
// holds the total; readlane broadcasts. Pure VALU, no lgkm traffic.
__device__ __forceinline__ float wave_allsum(float x) {
    int v = __builtin_bit_cast(int, x);
    v = fadd_i(v, __builtin_amdgcn_update_dpp(0, v, 0x111, 0xF, 0xF, true)); // row_shr:1
    v = fadd_i(v, __builtin_amdgcn_update_dpp(0, v, 0x112, 0xF, 0xF, true)); // row_shr:2
    v = fadd_i(v, __builtin_amdgcn_update_dpp(0, v, 0x114, 0xF, 0xF, true)); // row_shr:4
    v = fadd_i(v, __builtin_amdgcn_update_dpp(0, v, 0x118, 0xF, 0xF, true)); // row_shr:8
    v = fadd_i(v, __builtin_amdgcn_update_dpp(0, v, 0x142, 0xA, 0xF, true)); // row_bcast:15
    v = fadd_i(v, __builtin_amdgcn_update_dpp(0, v, 0x143, 0xC, 0xF, true)); // row_bcast:31
    return __builtin_bit_cast(float, __builtin_amdgcn_readlane(v, 63));
}

// packed fp32 fma: d = a*b + c on both 32-bit halves (one VOP3P inst)
__device__ __forceinline__ float2v pk_fma(float2v a, float2v b, float2v c) {
    float2v d;
    asm("v_pk_fma_f32 %0, %1, %2, %3" : "=v"(d) : "v"(a), "v"(b), "v"(c));
    return d;
}

__global__ __launch_bounds__(64, 1)
void exphydro_kernel(const float* __restrict__ g_snow, const float* __restrict__ g_water,
                     const float* __restrict__ g_pr, const float* __restrict__ g_tm,
                     const float* __restrict__ g_ld, const float* __restrict__ g_t,
                     const float* __restrict__ W1, const float* __restrict__ b1,
                     const float* __restrict__ W2, const float* __restrict__ b2,
                     const float* __restrict__ W3, const float* __restrict__ b3,
                     const float* __restrict__ W4, const float* __restrict__ b4,
                     float* __restrict__ out, int T)
{
    const int lane = threadIdx.x;
    const int b = blockIdx.x;

    // forcing interleaved per timestep: {pr, tm, ld, t} — one b128 read per point
    __shared__ __align__(16) float4v s_f[TMAX];
    __shared__ __align__(16) float hbuf[64];

    for (int i = lane; i < T; i += 64) {
        float4v v;
        v.x = g_pr[b * T + i];
        v.y = g_tm[b * T + i];
        v.z = g_ld[b * T + i];
        v.w = g_t[i];
        s_f[i] = v;
    }

    // weights: lane i holds column i of W1/W2/W3 (pair-packed) and row i of W4
    float w1r[4], w4r[5], b4r[5];
    float2v w2p[32], w3p[32];
#pragma unroll
    for (int j = 0; j < 4; ++j) w1r[j] = W1[j * 64 + lane];
    float b1v = b1[lane];
#pragma unroll
    for (int k = 0; k < 32; ++k) {
        w2p[k] = float2v{W2[(2 * k) * 64 + lane], W2[(2 * k + 1) * 64 + lane]};
        w3p[k] = float2v{W3[(2 * k) * 64 + lane], W3[(2 * k + 1) * 64 + lane]};
    }
    float b2v = b2[lane];
    float b3v = b3[lane];
#pragma unroll
    for (int k = 0; k < 5; ++k) { w4r[k] = W4[lane * 5 + k]; b4r[k] = b4[k]; }

    __syncthreads();

    // 64x64 matvec: broadcast x via LDS (single wave: DS pipe is in-order, no
    // barrier), packed-fp32 FMAs, 4 independent packed accumulator chains.
    auto matvec64 = [&](const float2v (&w)[32], float xlane, float bias) -> float {
        hbuf[lane] = xlane;
        float2v a0 = float2v{bias, 0.0f}, a1 = float2v{0.0f, 0.0f},
                a2 = float2v{0.0f, 0.0f}, a3 = float2v{0.0f, 0.0f};
#pragma unroll
        for (int j = 0; j < 64; j += 8) {
            float4v h0 = *reinterpret_cast<const float4v*>(&hbuf[j]);
            float4v h1 = *reinterpret_cast<const float4v*>(&hbuf[j + 4]);
            a0 = pk_fma(w[j / 2 + 0], __builtin_shufflevector(h0, h0, 0, 1), a0);
            a1 = pk_fma(w[j / 2 + 1], __builtin_shufflevector(h0, h0, 2, 3), a1);
            a2 = pk_fma(w[j / 2 + 2], __builtin_shufflevector(h1, h1, 0, 1), a2);
            a3 = pk_fma(w[j / 2 + 3], __builtin_shufflevector(h1, h1, 2, 3), a3);
        }
        float2v s = (a0 + a1) + (a2 + a3);
        return s.x + s.y;
    };

    // MLP given wave-uniform inputs; o[0..4] wave-uniform.
    auto mlp5 = [&](float x0, float x1, float x2, float x3, float* o) {
        float h1 = ftanh(fmaf(w1r[3], x3, fmaf(w1r[2], x2, fmaf(w1r[1], x1, fmaf(w1r[0], x0, b1v)))));
        float h2 = ftanh(matvec64(w2p, h1, b2v));
        float h3 = ftanh(matvec64(w3p, h2, b3v));
        float p0 = w4r[0] * h3, p1 = w4r[1] * h3, p2 = w4r[2] * h3,
              p3 = w4r[3] * h3, p4 = w4r[4] * h3;
        o[0] = wave_allsum(p0) + b4r[0];
        o[1] = wave_allsum(p1) + b4r[1];
        o[2] = wave_allsum(p2) + b4r[2];
        o[3] = wave_allsum(p3) + b4r[3];
        o[4] = wave_allsum(p4) + b4r[4];
    };

    // rhs with pre-hoisted forcing-derived terms: stepNT = fstep(-tm), ld.
    auto rhs = [&](float y0v, float y1v, float pr, float tm, float ld, float stepNT,
                   float& d0, float& d1, float& o4) {
        float o[5];
        mlp5(y0v, y1v, pr, tm, o);
        float psnow = fmaxf(0.0f, fsinh(o[0]) * stepNT);
        float prain = fmaxf(0.0f, fsinh(o[1]));
        float melt  = fmaxf(0.0f, fstep(y0v) * fsinh(o[2]));
        float st1   = fstep(y1v);
        float et    = st1 * fexp(o[3]) * ld;
        float qq    = st1 * fexp(o[4]);
        d0 = psnow - melt;
        d1 = prain + melt - et - qq;
        o4 = o[4];
    };

    float y0v = g_snow[b * T];
    float y1v = g_water[b * T];

    for (int st = 0; st < T - 1; ++st) {
        // time_series is arange: interp points are f[st], midpoint avg, f[st+1]
        float4v f0 = s_f[st];
        float4v f1 = s_f[st + 1];
        float dt = f1.w - f0.w, half = 0.5f * dt;
        float prH = 0.5f * (f0.x + f1.x);
        float tmH = 0.5f * (f0.y + f1.y);
        float ldH = 0.5f * (f0.z + f1.z);
        // forcing-only nonlinearities hoisted off the rhs dependency chains
        float stepA = fstep(-f0.y), stepH = fstep(-tmH), stepC = fstep(-f1.y);

        float k1a, k1b, k2a, k2b, k3a, k3b, k4a, k4b, o4, o4x;
        rhs(y0v, y1v, f0.x, f0.y, f0.z, stepA, k1a, k1b, o4);
        // q_out[:, st] == o[4] of the k1 MLP eval (integer-time interp == raw series)
        if (lane == 0) out[b * T + st] = o4;
        rhs(y0v + half * k1a, y1v + half * k1b, prH, tmH, ldH, stepH, k2a, k2b, o4x);
        rhs(y0v + half * k2a, y1v + half * k2b, prH, tmH, ldH, stepH, k3a, k3b, o4x);
        rhs(y0v + dt * k3a,   y1v + dt * k3b,  f1.x, f1.y, f1.z, stepC, k4a, k4b, o4x);

        float c = dt * (1.0f / 6.0f);
        y0v = fmaf(c, k1a + 2.0f * k2a + 2.0f * k3a + k4a, y0v);
        y1v = fmaf(c, k1b + 2.0f * k2b + 2.0f * k3b + k4b, y1v);
    }

    // last readout at t = T-1 with raw series values and final state
    {
        float4v fL = s_f[T - 1];
        float o[5];
        mlp5(y0v, y1v, fL.x, fL.y, o);
        if (lane == 0) out[b * T + (T - 1)] = o[4];
    }
}

extern "C" void kernel_launch(void* const* d_in, const int* in_sizes, int n_in,
                              void* d_out, int out_size, void* d_ws, size_t ws_size,
                              hipStream_t stream) {
    const float* g_snow  = (const float*)d_in[0];
    const float* g_water = (const float*)d_in[1];
    const float* g_pr    = (const float*)d_in[2];
    const float* g_tm    = (const float*)d_in[3];
    const float* g_ld    = (const float*)d_in[4];
    const float* g_t     = (const float*)d_in[5];
    const float* W1 = (const float*)d_in[6];
    const float* b1 = (const float*)d_in[7];
    const float* W2 = (const float*)d_in[8];
    const float* b2 = (const float*)d_in[9];
    const float* W3 = (const float*)d_in[10];
    const float* b3 = (const float*)d_in[11];
    const float* W4 = (const float*)d_in[12];
    const float* b4 = (const float*)d_in[13];

    const int T = in_sizes[5];
    const int B = in_sizes[0] / T;

    exphydro_kernel<<<dim3(B), dim3(64), 0, stream>>>(
        g_snow, g_water, g_pr, g_tm, g_ld, g_t,
        W1, b1, W2, b2, W3, b3, W4, b4,
        (float*)d_out, T);
}